// Round 8
// baseline (3390.660 us; speedup 1.0000x reference)
//
#include <hip/hip_runtime.h>
#include <cstdint>
#include <cstddef>

#define T_SEQ 1024
#define BATCH 64
#define DIM   256
#define HID   256
#define NG    (4*HID)   // 1024 gate columns, jp = 4r + g, g in {f,i,g~,o}

typedef _Float16 half8 __attribute__((ext_vector_type(8)));
typedef float f32x4 __attribute__((ext_vector_type(4)));
union U16H { uint4 u; half8 h; };

__device__ __forceinline__ float sigm_f(float x) {
    return 1.0f / (1.0f + __expf(-x));
}
__device__ __forceinline__ float tanh_f(float x) {
    x = fminf(fmaxf(x, -15.0f), 15.0f);   // avoid inf/inf
    float e = __expf(2.0f * x);
    return (e - 1.0f) / (e + 1.0f);
}

// quad_perm DPP (VALU pipe — keeps gate exchange off the LDS pipe)
#define QPERM(x, c) __int_as_float(__builtin_amdgcn_mov_dpp(__float_as_int(x), (c), 0xf, 0xf, true))

// ---------------- phase 0: repack weights, zero state -------------------------
// wx4[k*1024 + jp] = W_g[r][k]        (x part, fp32; jp = r*4+g)
// whB: h-part weights in MFMA B-fragment order (fp16):
//   element (k, jp): kt=k>>5, q=(k>>3)&3, s=k&7, T=jp>>4, lane=q*16+(jp&15)
//   whB[((kt*64 + T)*64 + lane)*8 + s] = fp16(W_g[r][256+k])
// bias folded into xproj via bias4[jp] = b_g[r]
// (layout identical to round-3 kernel, which passed the harness)
__global__ void pack_kernel(const float* __restrict__ Wf, const float* __restrict__ bf,
                            const float* __restrict__ Wi, const float* __restrict__ bi,
                            const float* __restrict__ Wg, const float* __restrict__ bg,
                            const float* __restrict__ Wo, const float* __restrict__ bo,
                            float* __restrict__ wx4, _Float16* __restrict__ whB,
                            float* __restrict__ bias4,
                            float* __restrict__ hstate, float* __restrict__ cstate) {
    int k = blockIdx.x;          // 0..255
    int j = threadIdx.x;         // 0..1023
    int r = j & 255, g = j >> 8;
    const float* W  = (g == 0) ? Wf : (g == 1) ? Wi : (g == 2) ? Wg : Wo;
    const float* bb = (g == 0) ? bf : (g == 1) ? bi : (g == 2) ? bg : bo;
    int jp = r * 4 + g;          // gate-interleaved column index
    wx4[(size_t)k * 1024 + jp] = W[(size_t)r * 512 + k];
    {
        int kt = k >> 5, q = (k >> 3) & 3, s = k & 7;
        int T = jp >> 4, lane = q * 16 + (jp & 15);
        whB[(((size_t)kt * 64 + T) * 64 + lane) * 8 + s] = (_Float16)W[(size_t)r * 512 + 256 + k];
    }
    if (k == 0) bias4[jp] = bb[r];
    if (k < 64 && g == 0) hstate[k * 256 + r] = 0.0f;
    if (k < 64 && g == 1) cstate[k * 256 + r] = 0.0f;
}

// ---------------- phase 1: Xproj ----------------------------------------------
// xp[row][jp] with jp = tid*4+g contiguous -> float4 stores; recurrence reads
// 8 coalesced scalars per lane (addresses fixed across steps).
__global__ __launch_bounds__(256) void xproj_kernel(
        const float* __restrict__ X, const float* __restrict__ wx4,
        const float* __restrict__ bias4, float4* __restrict__ xp) {
    __shared__ __align__(16) float xl[256 * 20];   // [k][row] padded
    int tid = threadIdx.x;
    int R0 = blockIdx.x * 16;
    #pragma unroll
    for (int i = 0; i < 16; ++i)
        xl[tid * 20 + i] = X[(size_t)(R0 + i) * DIM + tid];
    __syncthreads();

    float4 bv = ((const float4*)bias4)[tid];
    float acc[16][4];
    #pragma unroll
    for (int i = 0; i < 16; ++i) {
        acc[i][0] = bv.x; acc[i][1] = bv.y; acc[i][2] = bv.z; acc[i][3] = bv.w;
    }
    const float4* __restrict__ wp = (const float4*)wx4 + tid;
    #pragma unroll 2
    for (int k = 0; k < 256; ++k) {
        float4 w  = wp[k << 8];
        float4 xa = *(const float4*)&xl[k * 20 + 0];
        float4 xb = *(const float4*)&xl[k * 20 + 4];
        float4 xc = *(const float4*)&xl[k * 20 + 8];
        float4 xd = *(const float4*)&xl[k * 20 + 12];
        float xr[16] = {xa.x, xa.y, xa.z, xa.w, xb.x, xb.y, xb.z, xb.w,
                        xc.x, xc.y, xc.z, xc.w, xd.x, xd.y, xd.z, xd.w};
        #pragma unroll
        for (int i = 0; i < 16; ++i) {
            acc[i][0] = fmaf(xr[i], w.x, acc[i][0]);
            acc[i][1] = fmaf(xr[i], w.y, acc[i][1]);
            acc[i][2] = fmaf(xr[i], w.z, acc[i][2]);
            acc[i][3] = fmaf(xr[i], w.w, acc[i][3]);
        }
    }
    #pragma unroll
    for (int i = 0; i < 16; ++i) {
        float4 v;
        v.x = acc[i][0]; v.y = acc[i][1]; v.z = acc[i][2]; v.w = acc[i][3];
        xp[(size_t)(R0 + i) * 256 + tid] = v;   // row*1024 + tid*4 .. +3 (jp order)
    }
}

// ---------------- phase 2: MFMA recurrence, 1 WG (8 waves) per batch ---------
// gates[1024] = h[256] @ Wh[256][1024] via mfma_f32_16x16x32_f16, M=16 with
// identical A rows (h broadcast) -> only D's col=lane&15 mapping matters
// (verified end-to-end in round 3). 512 threads = 8 waves, 2 waves/SIMD
// (the latency-hiding round 3 lacked). Wave w owns col-tiles T=w*8..w*8+7.
// Weights: kt 0,1 in LDS (128 KB); kt 2..7 in 48 uint4/thread, AGPR-resident
// and consumed NATIVELY by MFMA (no v_accvgpr move tax, unlike fdot2).
// xa issued at step top, folded in at the epilogue (MFMA phase hides L2 lat).
// One barrier/step; h double-buffered in LDS; c in regs; DPP gate exchange.
__global__ __launch_bounds__(512, 2) void lstm_step_kernel(
        const float* __restrict__ xp, const _Float16* __restrict__ whB,
        float* __restrict__ hstate, float* __restrict__ cstate,
        float* __restrict__ out, int t0, int Tc) {
    __shared__ __align__(16) _Float16 blds[2 * 64 * 64 * 8];   // 128 KB: kt = 0,1
    __shared__ __align__(16) _Float16 hl[2][HID];              // double-buffered h
    int tid = threadIdx.x, b = blockIdx.x;
    int l = tid & 63, w = tid >> 6;       // wave 0..7

    // stage kt=0,1 (8192 uint4 over 512 threads = 16 each)
    {
        const uint4* s4 = (const uint4*)whB;
        uint4* dst = (uint4*)blds;
        #pragma unroll
        for (int i = 0; i < 16; ++i)
            dst[i * 512 + tid] = s4[i * 512 + tid];
    }
    // register slab: kt = 2..7, 8 tiles each (48 uint4; AGPR-ok, MFMA-native)
    U16H wreg[6][8];
    {
        const uint4* s4 = (const uint4*)whB;
        #pragma unroll
        for (int kt = 0; kt < 6; ++kt)
            #pragma unroll
            for (int n = 0; n < 8; ++n)
                wreg[kt][n].u = s4[(size_t)((kt + 2) * 64 + w * 8 + n) * 64 + l];
    }
    // c state: one r-quad per (n, l>>2) in lanes 0..15 (replicated above)
    float c_reg[8];
    int rsub = (l & 15) >> 2;
    #pragma unroll
    for (int n = 0; n < 8; ++n)
        c_reg[n] = cstate[b * HID + (w * 8 + n) * 4 + rsub];
    if (tid < HID) hl[0][tid] = (_Float16)hstate[b * HID + tid];

    int g = l & 3;
    float sm = (g == 2) ? 2.0f : 1.0f;            // tanh(x) = 2*sigm(2x)-1
    float aa = sm, bbc = (g == 2) ? -1.0f : 0.0f;
    bool wmask = (l < 16) && ((l & 3) == 0);
    __syncthreads();

    int cur = 0;
    for (int tt = 0; tt < Tc; ++tt) {
        // xa issued first, consumed in the epilogue (hidden under MFMAs)
        float xa[8];
        {
            const float* xr = xp + ((size_t)tt * BATCH + b) * NG + w * 128 + (l & 15);
            #pragma unroll
            for (int n = 0; n < 8; ++n) xa[n] = xr[n * 16];
        }
        const _Float16* hb = hl[cur];
        f32x4 acc[8];
        #pragma unroll
        for (int n = 0; n < 8; ++n) acc[n] = (f32x4){0.f, 0.f, 0.f, 0.f};
        // kt 2..7 from registers (AGPR-native MFMA operands)
        #pragma unroll
        for (int kt = 0; kt < 6; ++kt) {
            U16H af; af.u = *(const uint4*)&hb[(kt + 2) * 32 + (l >> 4) * 8];
            #pragma unroll
            for (int n = 0; n < 8; ++n)
                acc[n] = __builtin_amdgcn_mfma_f32_16x16x32_f16(
                    af.h, wreg[kt][n].h, acc[n], 0, 0, 0);
        }
        // kt 0,1 from LDS
        #pragma unroll
        for (int kt = 0; kt < 2; ++kt) {
            U16H af; af.u = *(const uint4*)&hb[kt * 32 + (l >> 4) * 8];
            #pragma unroll
            for (int n = 0; n < 8; ++n) {
                U16H bf;
                bf.u = *((const uint4*)blds + (size_t)(kt * 64 + w * 8 + n) * 64 + l);
                acc[n] = __builtin_amdgcn_mfma_f32_16x16x32_f16(
                    af.h, bf.h, acc[n], 0, 0, 0);
            }
        }
        // epilogue: lane quad (l&3) holds (f,i,g~,o) of r = (w*8+n)*4 + (l>>2)
        #pragma unroll
        for (int n = 0; n < 8; ++n) {
            float y   = acc[n][0] + xa[n];
            float s   = sigm_f(sm * y);
            float val = fmaf(aa, s, bbc);       // f/i/o: sigm, g~: tanh
            float t3  = QPERM(val, 0x1B);       // reverse within quad
            float m1  = val * t3;               // lanes 1,2: i*g~
            float ig  = QPERM(m1, 0x55);        // all <- quad-lane 1: i*g~
            float ff  = QPERM(val, 0x00);       // all <- quad-lane 0: f
            float oo  = QPERM(val, 0xFF);       // all <- quad-lane 3: o
            float c   = fmaf(ff, c_reg[n], ig);
            c_reg[n]  = c;
            float h   = oo * tanh_f(c);
            if (wmask) hl[cur ^ 1][(w * 8 + n) * 4 + (l >> 2)] = (_Float16)h;
        }
        __syncthreads();
        // coalesced out-store post-barrier (ack drains at next step's barrier)
        if (tid < HID)
            out[((size_t)(t0 + tt) * BATCH + b) * HID + tid] = (float)hl[cur ^ 1][tid];
        cur ^= 1;
    }
    if (tid < HID) hstate[b * HID + tid] = (float)hl[cur][tid];
    if (wmask) {
        #pragma unroll
        for (int n = 0; n < 8; ++n)
            cstate[b * HID + (w * 8 + n) * 4 + (l >> 2)] = c_reg[n];
    }
}

// ---------------- tail: final hx, cx ------------------------------------------
__global__ void tail_kernel(const float* __restrict__ hstate,
                            const float* __restrict__ cstate, float* __restrict__ out) {
    int b = blockIdx.x, r = threadIdx.x;
    size_t base = (size_t)T_SEQ * BATCH * HID;
    out[base + b * HID + r] = hstate[b * HID + r];
    out[base + (size_t)BATCH * HID + b * HID + r] = cstate[b * HID + r];
}

extern "C" void kernel_launch(void* const* d_in, const int* in_sizes, int n_in,
                              void* d_out, int out_size, void* d_ws, size_t ws_size,
                              hipStream_t stream) {
    (void)in_sizes; (void)n_in; (void)out_size;
    const float* X  = (const float*)d_in[0];
    const float* Wf = (const float*)d_in[1];
    const float* bf = (const float*)d_in[2];
    const float* Wi = (const float*)d_in[3];
    const float* bi = (const float*)d_in[4];
    const float* Wg = (const float*)d_in[5];
    const float* bg = (const float*)d_in[6];
    const float* Wo = (const float*)d_in[7];
    const float* bo = (const float*)d_in[8];
    float* out = (float*)d_out;
    char*  ws  = (char*)d_ws;

    const size_t MB = 1 << 20, KB = 1 << 10;
    float*    wx4    = (float*)(ws);                          // 1 MB
    _Float16* whB    = (_Float16*)(ws + MB);                  // 512 KB
    float*    bias4  = (float*)(ws + MB + 512 * KB);          // 4 KB
    float*    hstate = (float*)(ws + MB + 576 * KB);          // 64 KB
    float*    cstate = (float*)(ws + MB + 640 * KB);          // 64 KB
    float4*   xproj  = (float4*)(ws + 2 * MB);

    size_t fixed = 2 * MB;
    int Tc = 1024;
    while (Tc > 16 && fixed + (size_t)Tc * BATCH * NG * 4 > ws_size) Tc >>= 1;

    pack_kernel<<<256, 1024, 0, stream>>>(Wf, bf, Wi, bi, Wg, bg, Wo, bo,
                                          wx4, whB, bias4, hstate, cstate);
    for (int t0 = 0; t0 < T_SEQ; t0 += Tc) {
        xproj_kernel<<<Tc * BATCH / 16, 256, 0, stream>>>(
            X + (size_t)t0 * BATCH * DIM, wx4, bias4, xproj);
        lstm_step_kernel<<<BATCH, 512, 0, stream>>>(
            (const float*)xproj, whB, hstate, cstate, out, t0, Tc);
    }
    tail_kernel<<<BATCH, HID, 0, stream>>>(hstate, cstate, out);
}

// Round 9
// 2069.266 us; speedup vs baseline: 1.6386x; 1.6386x over previous
//
#include <hip/hip_runtime.h>
#include <cstdint>
#include <cstddef>

#define T_SEQ 1024
#define BATCH 64
#define DIM   256
#define HID   256
#define NG    (4*HID)   // 1024 gate columns, jp = 4r + g, g in {f,i,g~,o}

typedef _Float16 h2v __attribute__((ext_vector_type(2)));
union U16 { uint4 u; h2v h[4]; };

__device__ __forceinline__ float sigm_f(float x) {
    return 1.0f / (1.0f + __expf(-x));
}
__device__ __forceinline__ float tanh_f(float x) {
    x = fminf(fmaxf(x, -15.0f), 15.0f);   // avoid inf/inf
    float e = __expf(2.0f * x);
    return (e - 1.0f) / (e + 1.0f);
}

// DPP quad_perm [1,0,3,2] = swap adjacent lane pairs (xor-1), VALU pipe
#define QP_XOR1(x) __int_as_float(__builtin_amdgcn_mov_dpp(__float_as_int(x), 0xB1, 0xf, 0xf, true))

// ---------------- phase 0: repack weights, zero state -------------------------
// wx4[k*1024 + jp] = W_g[r][k]            (x part, fp32; jp = 4r+g)
// whB (h part, fp16, k-packs of 8), PAIR-K-SPLIT layout:
//   chunk c = k>>3 (0..31), e = k&7; col jp: R = jp>>2, s = jp&3.
//   k-half p = (c>=16); reader thread t = 2R + p; lc = c - 16p (0..15).
//   lc 0..3  -> LDS region:  uint4 idx =        (lc*4 + s)*512 + t
//   lc 4..15 -> reg region:  uint4 idx = 8192 + ((lc-4)*4 + s)*512 + t
// bias4[jp] = b_g[r]
__global__ void pack_kernel(const float* __restrict__ Wf, const float* __restrict__ bf,
                            const float* __restrict__ Wi, const float* __restrict__ bi,
                            const float* __restrict__ Wg, const float* __restrict__ bg,
                            const float* __restrict__ Wo, const float* __restrict__ bo,
                            float* __restrict__ wx4, _Float16* __restrict__ whB,
                            float* __restrict__ bias4,
                            float* __restrict__ hstate, float* __restrict__ cstate) {
    int k = blockIdx.x;          // 0..255
    int j = threadIdx.x;         // 0..1023
    int r = j & 255, g = j >> 8;
    const float* W  = (g == 0) ? Wf : (g == 1) ? Wi : (g == 2) ? Wg : Wo;
    const float* bb = (g == 0) ? bf : (g == 1) ? bi : (g == 2) ? bg : bo;
    int jp = r * 4 + g;
    wx4[(size_t)k * 1024 + jp] = W[(size_t)r * 512 + k];
    {
        int c = k >> 3, e = k & 7;
        int R = jp >> 2, s = jp & 3;
        int p = (c >= 16) ? 1 : 0;
        int lc = c - 16 * p;                 // 0..15
        int t = 2 * R + p;
        size_t idx = (lc < 4)
            ? ((size_t)(lc * 4 + s) * 512 + t)
            : (8192 + (size_t)((lc - 4) * 4 + s) * 512 + t);
        whB[idx * 8 + e] = (_Float16)W[(size_t)r * 512 + 256 + k];
    }
    if (k == 0) bias4[jp] = bb[r];
    if (k < 64 && g == 0) hstate[k * 256 + r] = 0.0f;
    if (k < 64 && g == 1) cstate[k * 256 + r] = 0.0f;
}

// ---------------- phase 1: Xproj ----------------------------------------------
// xp[row][jp] with jp = tid*4+g contiguous (float4 per r) -> the recurrence
// reads ONE float2 (cols 2t, 2t+1) per step per thread.
__global__ __launch_bounds__(256) void xproj_kernel(
        const float* __restrict__ X, const float* __restrict__ wx4,
        const float* __restrict__ bias4, float4* __restrict__ xp) {
    __shared__ __align__(16) float xl[256 * 20];   // [k][row] padded
    int tid = threadIdx.x;
    int R0 = blockIdx.x * 16;
    #pragma unroll
    for (int i = 0; i < 16; ++i)
        xl[tid * 20 + i] = X[(size_t)(R0 + i) * DIM + tid];
    __syncthreads();

    float4 bv = ((const float4*)bias4)[tid];
    float acc[16][4];
    #pragma unroll
    for (int i = 0; i < 16; ++i) {
        acc[i][0] = bv.x; acc[i][1] = bv.y; acc[i][2] = bv.z; acc[i][3] = bv.w;
    }
    const float4* __restrict__ wp = (const float4*)wx4 + tid;
    #pragma unroll 2
    for (int k = 0; k < 256; ++k) {
        float4 w  = wp[k << 8];
        float4 xa = *(const float4*)&xl[k * 20 + 0];
        float4 xb = *(const float4*)&xl[k * 20 + 4];
        float4 xc = *(const float4*)&xl[k * 20 + 8];
        float4 xd = *(const float4*)&xl[k * 20 + 12];
        float xr[16] = {xa.x, xa.y, xa.z, xa.w, xb.x, xb.y, xb.z, xb.w,
                        xc.x, xc.y, xc.z, xc.w, xd.x, xd.y, xd.z, xd.w};
        #pragma unroll
        for (int i = 0; i < 16; ++i) {
            acc[i][0] = fmaf(xr[i], w.x, acc[i][0]);
            acc[i][1] = fmaf(xr[i], w.y, acc[i][1]);
            acc[i][2] = fmaf(xr[i], w.z, acc[i][2]);
            acc[i][3] = fmaf(xr[i], w.w, acc[i][3]);
        }
    }
    #pragma unroll
    for (int i = 0; i < 16; ++i) {
        float4 v;
        v.x = acc[i][0]; v.y = acc[i][1]; v.z = acc[i][2]; v.w = acc[i][3];
        xp[(size_t)(R0 + i) * 256 + tid] = v;
    }
}

// ---------------- phase 2: sequential recurrence, 1 WG per batch element -----
// 512 threads (8 waves, 2/SIMD). PAIR-K-SPLIT: lane pair (2R, 2R+1) owns all
// 4 gate cols of row R. Even thread computes k-half-0 partials of all 4 cols
// (h-broadcast chunks 0..15 only); odd thread k-half-1 (chunks 16..31).
// 4 DPP xor-1 exchanges combine partials; each thread finishes cols 2t,2t+1
// exactly as round-4 (same xa/out/activation mapping). h-broadcast LDS reads
// per thread: 32 -> 16; weight reads stay 16 (lane-linear, conflict-free).
// One barrier/step, hl double-buffered, out-store post-barrier (r4 shell).
__global__ __launch_bounds__(512, 2) void lstm_step_kernel(
        const float* __restrict__ xp, const _Float16* __restrict__ whB,
        float* __restrict__ hstate, float* __restrict__ cstate,
        float* __restrict__ out, int t0, int Tc) {
    __shared__ __align__(16) _Float16 wl[16 * 512 * 8];   // 128 KB: lc 0..3 both halves
    __shared__ __align__(16) _Float16 hl[2][HID];         // double-buffered h
    int t = threadIdx.x, b = blockIdx.x;

    // stage LDS region (8192 uint4 over 512 threads = 16 each)
    {
        const uint4* src = (const uint4*)whB;
        uint4* dst = (uint4*)wl;
        #pragma unroll
        for (int i = 0; i < 16; ++i)
            dst[i * 512 + t] = src[i * 512 + t];
    }
    // register slab: 12 chunks x 4 cols for this thread's k-half (48 uint4)
    uint4 wrg[12][4];
    {
        const uint4* src = (const uint4*)whB + 8192;
        #pragma unroll
        for (int i = 0; i < 12; ++i)
            #pragma unroll
            for (int s = 0; s < 4; ++s)
                wrg[i][s] = src[(size_t)((i * 4 + s) * 512) + t];
    }
    int podd = t & 1;
    int cb = podd << 4;                            // h-chunk base: 0 or 16
    float creg = cstate[b * HID + (t >> 1)];       // pair-replicated (row R)
    if (t < HID) hl[0][t] = (_Float16)hstate[b * HID + t];
    // branchless gate-A activation: even: sigm(x); odd: tanh(x)=2*sigm(2x)-1
    float sm = podd ? 2.0f : 1.0f;
    float aa = sm, bbc = podd ? -1.0f : 0.0f;
    __syncthreads();

    const float2* __restrict__ xpf2 = (const float2*)xp;
    float2 xa2 = xpf2[(size_t)b * 512 + t];
    int cur = 0;
    for (int tt = 0; tt < Tc; ++tt) {
        // prefetch next step's xp early (hides latency under the dot chain)
        int tn = (tt + 1 < Tc) ? tt + 1 : tt;
        float2 xn2 = xpf2[((size_t)tn * BATCH + b) * 512 + t];

        float sA0 = 0.f, sB0 = 0.f, sA1 = 0.f, sB1 = 0.f;
        float sA2 = 0.f, sB2 = 0.f, sA3 = 0.f, sB3 = 0.f;
        const _Float16* hb = hl[cur];
        // LDS-weight chunks lc = 0..3 of this thread's k-half
        #pragma unroll
        for (int lc = 0; lc < 4; ++lc) {
            U16 h; h.u = *(const uint4*)&hb[(cb + lc) * 8];           // 2-addr bcast
            U16 w0, w1, w2, w3;
            w0.u = *(const uint4*)&wl[((size_t)((lc * 4 + 0) * 512 + t)) * 8];
            w1.u = *(const uint4*)&wl[((size_t)((lc * 4 + 1) * 512 + t)) * 8];
            w2.u = *(const uint4*)&wl[((size_t)((lc * 4 + 2) * 512 + t)) * 8];
            w3.u = *(const uint4*)&wl[((size_t)((lc * 4 + 3) * 512 + t)) * 8];
            sA0 = __builtin_amdgcn_fdot2(w0.h[0], h.h[0], sA0, false);
            sB0 = __builtin_amdgcn_fdot2(w0.h[1], h.h[1], sB0, false);
            sA0 = __builtin_amdgcn_fdot2(w0.h[2], h.h[2], sA0, false);
            sB0 = __builtin_amdgcn_fdot2(w0.h[3], h.h[3], sB0, false);
            sA1 = __builtin_amdgcn_fdot2(w1.h[0], h.h[0], sA1, false);
            sB1 = __builtin_amdgcn_fdot2(w1.h[1], h.h[1], sB1, false);
            sA1 = __builtin_amdgcn_fdot2(w1.h[2], h.h[2], sA1, false);
            sB1 = __builtin_amdgcn_fdot2(w1.h[3], h.h[3], sB1, false);
            sA2 = __builtin_amdgcn_fdot2(w2.h[0], h.h[0], sA2, false);
            sB2 = __builtin_amdgcn_fdot2(w2.h[1], h.h[1], sB2, false);
            sA2 = __builtin_amdgcn_fdot2(w2.h[2], h.h[2], sA2, false);
            sB2 = __builtin_amdgcn_fdot2(w2.h[3], h.h[3], sB2, false);
            sA3 = __builtin_amdgcn_fdot2(w3.h[0], h.h[0], sA3, false);
            sB3 = __builtin_amdgcn_fdot2(w3.h[1], h.h[1], sB3, false);
            sA3 = __builtin_amdgcn_fdot2(w3.h[2], h.h[2], sA3, false);
            sB3 = __builtin_amdgcn_fdot2(w3.h[3], h.h[3], sB3, false);
        }
        // register-weight chunks i = 0..11 (global chunk cb + 4 + i)
        #pragma unroll
        for (int i = 0; i < 12; ++i) {
            U16 h; h.u = *(const uint4*)&hb[(cb + 4 + i) * 8];        // 2-addr bcast
            U16 w0, w1, w2, w3;
            w0.u = wrg[i][0]; w1.u = wrg[i][1]; w2.u = wrg[i][2]; w3.u = wrg[i][3];
            sA0 = __builtin_amdgcn_fdot2(w0.h[0], h.h[0], sA0, false);
            sB0 = __builtin_amdgcn_fdot2(w0.h[1], h.h[1], sB0, false);
            sA0 = __builtin_amdgcn_fdot2(w0.h[2], h.h[2], sA0, false);
            sB0 = __builtin_amdgcn_fdot2(w0.h[3], h.h[3], sB0, false);
            sA1 = __builtin_amdgcn_fdot2(w1.h[0], h.h[0], sA1, false);
            sB1 = __builtin_amdgcn_fdot2(w1.h[1], h.h[1], sB1, false);
            sA1 = __builtin_amdgcn_fdot2(w1.h[2], h.h[2], sA1, false);
            sB1 = __builtin_amdgcn_fdot2(w1.h[3], h.h[3], sB1, false);
            sA2 = __builtin_amdgcn_fdot2(w2.h[0], h.h[0], sA2, false);
            sB2 = __builtin_amdgcn_fdot2(w2.h[1], h.h[1], sB2, false);
            sA2 = __builtin_amdgcn_fdot2(w2.h[2], h.h[2], sA2, false);
            sB2 = __builtin_amdgcn_fdot2(w2.h[3], h.h[3], sB2, false);
            sA3 = __builtin_amdgcn_fdot2(w3.h[0], h.h[0], sA3, false);
            sB3 = __builtin_amdgcn_fdot2(w3.h[1], h.h[1], sB3, false);
            sA3 = __builtin_amdgcn_fdot2(w3.h[2], h.h[2], sA3, false);
            sB3 = __builtin_amdgcn_fdot2(w3.h[3], h.h[3], sB3, false);
        }
        // combine k-halves across the lane pair (DPP, VALU pipe)
        float P0 = sA0 + sB0, P1 = sA1 + sB1, P2 = sA2 + sB2, P3 = sA3 + sB3;
        float S0 = P0 + QP_XOR1(P0);     // full dot, col 4R+0 (f)
        float S1 = P1 + QP_XOR1(P1);     // col 4R+1 (i)
        float S2 = P2 + QP_XOR1(P2);     // col 4R+2 (g~)
        float S3 = P3 + QP_XOR1(P3);     // col 4R+3 (o)
        float a0 = xa2.x + (podd ? S2 : S0);   // col 2t   (even: f | odd: g~)
        float a1 = xa2.y + (podd ? S3 : S1);   // col 2t+1 (even: i | odd: o)
        float vA = fmaf(aa, sigm_f(sm * a0), bbc);
        float vB = sigm_f(a1);
        float eA = QP_XOR1(vA);            // partner's A value
        float eB = QP_XOR1(vB);            // partner's B value
        float f  = podd ? eA : vA;
        float ii = podd ? eB : vB;
        float gg = podd ? vA : eA;
        float o  = podd ? vB : eB;
        float c  = fmaf(f, creg, ii * gg);
        creg = c;
        float h  = o * tanh_f(c);
        if (!podd) hl[cur ^ 1][t >> 1] = (_Float16)h;
        __syncthreads();
        // coalesced out-store post-barrier (drains at next step's barrier)
        if (t < HID)
            out[((size_t)(t0 + tt) * BATCH + b) * HID + t] = (float)hl[cur ^ 1][t];
        xa2 = xn2;
        cur ^= 1;
    }
    if (t < HID) hstate[b * HID + t] = (float)hl[cur][t];
    if (!podd)   cstate[b * HID + (t >> 1)] = creg;
}

// ---------------- tail: final hx, cx ------------------------------------------
__global__ void tail_kernel(const float* __restrict__ hstate,
                            const float* __restrict__ cstate, float* __restrict__ out) {
    int b = blockIdx.x, r = threadIdx.x;
    size_t base = (size_t)T_SEQ * BATCH * HID;
    out[base + b * HID + r] = hstate[b * HID + r];
    out[base + (size_t)BATCH * HID + b * HID + r] = cstate[b * HID + r];
}

extern "C" void kernel_launch(void* const* d_in, const int* in_sizes, int n_in,
                              void* d_out, int out_size, void* d_ws, size_t ws_size,
                              hipStream_t stream) {
    (void)in_sizes; (void)n_in; (void)out_size;
    const float* X  = (const float*)d_in[0];
    const float* Wf = (const float*)d_in[1];
    const float* bf = (const float*)d_in[2];
    const float* Wi = (const float*)d_in[3];
    const float* bi = (const float*)d_in[4];
    const float* Wg = (const float*)d_in[5];
    const float* bg = (const float*)d_in[6];
    const float* Wo = (const float*)d_in[7];
    const float* bo = (const float*)d_in[8];
    float* out = (float*)d_out;
    char*  ws  = (char*)d_ws;

    const size_t MB = 1 << 20, KB = 1 << 10;
    float*    wx4    = (float*)(ws);                          // 1 MB
    _Float16* whB    = (_Float16*)(ws + MB);                  // 512 KB
    float*    bias4  = (float*)(ws + MB + 512 * KB);          // 4 KB
    float*    hstate = (float*)(ws + MB + 576 * KB);          // 64 KB
    float*    cstate = (float*)(ws + MB + 640 * KB);          // 64 KB
    float4*   xproj  = (float4*)(ws + 2 * MB);

    size_t fixed = 2 * MB;
    int Tc = 1024;
    while (Tc > 16 && fixed + (size_t)Tc * BATCH * NG * 4 > ws_size) Tc >>= 1;

    pack_kernel<<<256, 1024, 0, stream>>>(Wf, bf, Wi, bi, Wg, bg, Wo, bo,
                                          wx4, whB, bias4, hstate, cstate);
    for (int t0 = 0; t0 < T_SEQ; t0 += Tc) {
        xproj_kernel<<<Tc * BATCH / 16, 256, 0, stream>>>(
            X + (size_t)t0 * BATCH * DIM, wx4, bias4, xproj);
        lstm_step_kernel<<<BATCH, 512, 0, stream>>>(
            (const float*)xproj, whB, hstate, cstate, out, t0, Tc);
    }
    tail_kernel<<<BATCH, HID, 0, stream>>>(hstate, cstate, out);
}

// Round 10
// 2011.349 us; speedup vs baseline: 1.6858x; 1.0288x over previous
//
#include <hip/hip_runtime.h>
#include <cstdint>
#include <cstddef>

#define T_SEQ 1024
#define BATCH 64
#define DIM   256
#define HID   256
#define NG    (4*HID)   // 1024 gate columns, jp = 4r + g, g in {f,i,g~,o}
#define HPADN (HID + 8) // h buffer with 16B pad between row-halves (bank shift)

typedef _Float16 h2v __attribute__((ext_vector_type(2)));
union U16 { uint4 u; h2v h[4]; };

__device__ __forceinline__ float sigm_f(float x) {
    return 1.0f / (1.0f + __expf(-x));
}
__device__ __forceinline__ float tanh_f(float x) {
    x = fminf(fmaxf(x, -15.0f), 15.0f);   // avoid inf/inf
    float e = __expf(2.0f * x);
    return (e - 1.0f) / (e + 1.0f);
}

// DPP quad_perm [1,0,3,2] = swap adjacent lane pairs (xor-1), VALU pipe
#define QP_XOR1(x) __int_as_float(__builtin_amdgcn_mov_dpp(__float_as_int(x), 0xB1, 0xf, 0xf, true))

// padded h index: rows 128..255 shifted by 8 halfs (16B) so the odd-lane
// broadcast (chunk-half 1) lands on different banks than chunk-half 0
__device__ __forceinline__ int hpad(int r) { return r + ((r >> 7) << 3); }

// ---------------- phase 0: repack weights, zero state -------------------------
// wx4[k*1024 + jp] = W_g[r][k]            (x part, fp32; jp = 4r+g)
// whB (h part, fp16, k-packs of 8), PAIR-K-SPLIT layout:
//   chunk c = k>>3 (0..31), e = k&7; col jp: R = jp>>2, s = jp&3.
//   k-half p = (c>=16); reader thread t = 2R + p; lc = c - 16p (0..15).
//   lc 0..3  -> LDS region:  uint4 idx =        (lc*4 + s)*512 + t
//   lc 4..15 -> reg region:  uint4 idx = 8192 + ((lc-4)*4 + s)*512 + t
// bias4[jp] = b_g[r]
__global__ void pack_kernel(const float* __restrict__ Wf, const float* __restrict__ bf,
                            const float* __restrict__ Wi, const float* __restrict__ bi,
                            const float* __restrict__ Wg, const float* __restrict__ bg,
                            const float* __restrict__ Wo, const float* __restrict__ bo,
                            float* __restrict__ wx4, _Float16* __restrict__ whB,
                            float* __restrict__ bias4,
                            float* __restrict__ hstate, float* __restrict__ cstate) {
    int k = blockIdx.x;          // 0..255
    int j = threadIdx.x;         // 0..1023
    int r = j & 255, g = j >> 8;
    const float* W  = (g == 0) ? Wf : (g == 1) ? Wi : (g == 2) ? Wg : Wo;
    const float* bb = (g == 0) ? bf : (g == 1) ? bi : (g == 2) ? bg : bo;
    int jp = r * 4 + g;
    wx4[(size_t)k * 1024 + jp] = W[(size_t)r * 512 + k];
    {
        int c = k >> 3, e = k & 7;
        int R = jp >> 2, s = jp & 3;
        int p = (c >= 16) ? 1 : 0;
        int lc = c - 16 * p;                 // 0..15
        int t = 2 * R + p;
        size_t idx = (lc < 4)
            ? ((size_t)(lc * 4 + s) * 512 + t)
            : (8192 + (size_t)((lc - 4) * 4 + s) * 512 + t);
        whB[idx * 8 + e] = (_Float16)W[(size_t)r * 512 + 256 + k];
    }
    if (k == 0) bias4[jp] = bb[r];
    if (k < 64 && g == 0) hstate[k * 256 + r] = 0.0f;
    if (k < 64 && g == 1) cstate[k * 256 + r] = 0.0f;
}

// ---------------- phase 1: Xproj ----------------------------------------------
// xp[row][jp] with jp = tid*4+g contiguous (float4 per r) -> the recurrence
// reads ONE float2 (cols 2t, 2t+1) per step per thread.
__global__ __launch_bounds__(256) void xproj_kernel(
        const float* __restrict__ X, const float* __restrict__ wx4,
        const float* __restrict__ bias4, float4* __restrict__ xp) {
    __shared__ __align__(16) float xl[256 * 20];   // [k][row] padded
    int tid = threadIdx.x;
    int R0 = blockIdx.x * 16;
    #pragma unroll
    for (int i = 0; i < 16; ++i)
        xl[tid * 20 + i] = X[(size_t)(R0 + i) * DIM + tid];
    __syncthreads();

    float4 bv = ((const float4*)bias4)[tid];
    float acc[16][4];
    #pragma unroll
    for (int i = 0; i < 16; ++i) {
        acc[i][0] = bv.x; acc[i][1] = bv.y; acc[i][2] = bv.z; acc[i][3] = bv.w;
    }
    const float4* __restrict__ wp = (const float4*)wx4 + tid;
    #pragma unroll 2
    for (int k = 0; k < 256; ++k) {
        float4 w  = wp[k << 8];
        float4 xa = *(const float4*)&xl[k * 20 + 0];
        float4 xb = *(const float4*)&xl[k * 20 + 4];
        float4 xc = *(const float4*)&xl[k * 20 + 8];
        float4 xd = *(const float4*)&xl[k * 20 + 12];
        float xr[16] = {xa.x, xa.y, xa.z, xa.w, xb.x, xb.y, xb.z, xb.w,
                        xc.x, xc.y, xc.z, xc.w, xd.x, xd.y, xd.z, xd.w};
        #pragma unroll
        for (int i = 0; i < 16; ++i) {
            acc[i][0] = fmaf(xr[i], w.x, acc[i][0]);
            acc[i][1] = fmaf(xr[i], w.y, acc[i][1]);
            acc[i][2] = fmaf(xr[i], w.z, acc[i][2]);
            acc[i][3] = fmaf(xr[i], w.w, acc[i][3]);
        }
    }
    #pragma unroll
    for (int i = 0; i < 16; ++i) {
        float4 v;
        v.x = acc[i][0]; v.y = acc[i][1]; v.z = acc[i][2]; v.w = acc[i][3];
        xp[(size_t)(R0 + i) * 256 + tid] = v;
    }
}

// ---------------- phase 2: sequential recurrence, 1 WG per batch element -----
// 512 threads (8 waves, 2/SIMD). PAIR-K-SPLIT: lane pair (2R, 2R+1) owns all
// 4 gate cols of row R; even thread k-half 0 (h chunks 0..15), odd thread
// k-half 1 (chunks 16..31); 4 DPP xor-1 combines. Identical to round 9
// EXCEPT hl is padded (+8 halfs between row-halves): the two broadcast
// addresses per wave now hit DISJOINT bank groups -> conflict-free
// (round 9: 1.678e7 conflict cycles = exactly the intended h-read saving).
__global__ __launch_bounds__(512, 2) void lstm_step_kernel(
        const float* __restrict__ xp, const _Float16* __restrict__ whB,
        float* __restrict__ hstate, float* __restrict__ cstate,
        float* __restrict__ out, int t0, int Tc) {
    __shared__ __align__(16) _Float16 wl[16 * 512 * 8];   // 128 KB: lc 0..3 both halves
    __shared__ __align__(16) _Float16 hl[2][HPADN];       // padded, double-buffered h
    int t = threadIdx.x, b = blockIdx.x;

    // stage LDS region (8192 uint4 over 512 threads = 16 each)
    {
        const uint4* src = (const uint4*)whB;
        uint4* dst = (uint4*)wl;
        #pragma unroll
        for (int i = 0; i < 16; ++i)
            dst[i * 512 + t] = src[i * 512 + t];
    }
    // register slab: 12 chunks x 4 cols for this thread's k-half (48 uint4)
    uint4 wrg[12][4];
    {
        const uint4* src = (const uint4*)whB + 8192;
        #pragma unroll
        for (int i = 0; i < 12; ++i)
            #pragma unroll
            for (int s = 0; s < 4; ++s)
                wrg[i][s] = src[(size_t)((i * 4 + s) * 512) + t];
    }
    int podd = t & 1;
    float creg = cstate[b * HID + (t >> 1)];       // pair-replicated (row R)
    if (t < HID) hl[0][hpad(t)] = (_Float16)hstate[b * HID + t];
    // branchless gate-A activation: even: sigm(x); odd: tanh(x)=2*sigm(2x)-1
    float sm = podd ? 2.0f : 1.0f;
    float aa = sm, bbc = podd ? -1.0f : 0.0f;
    // padded h-chunk byte base: chunk cb+lc at halfs (cb+lc)*8 + podd*8
    int hbase = (podd << 7) + (podd << 3);         // cb*8 + pad = podd*(128+8)
    __syncthreads();

    const float2* __restrict__ xpf2 = (const float2*)xp;
    float2 xa2 = xpf2[(size_t)b * 512 + t];
    int cur = 0;
    for (int tt = 0; tt < Tc; ++tt) {
        // prefetch next step's xp early (hides latency under the dot chain)
        int tn = (tt + 1 < Tc) ? tt + 1 : tt;
        float2 xn2 = xpf2[((size_t)tn * BATCH + b) * 512 + t];

        float sA0 = 0.f, sB0 = 0.f, sA1 = 0.f, sB1 = 0.f;
        float sA2 = 0.f, sB2 = 0.f, sA3 = 0.f, sB3 = 0.f;
        const _Float16* hb = &hl[cur][hbase];
        // LDS-weight chunks lc = 0..3 of this thread's k-half
        #pragma unroll
        for (int lc = 0; lc < 4; ++lc) {
            U16 h; h.u = *(const uint4*)&hb[lc * 8];        // disjoint-bank bcast
            U16 w0, w1, w2, w3;
            w0.u = *(const uint4*)&wl[((size_t)((lc * 4 + 0) * 512 + t)) * 8];
            w1.u = *(const uint4*)&wl[((size_t)((lc * 4 + 1) * 512 + t)) * 8];
            w2.u = *(const uint4*)&wl[((size_t)((lc * 4 + 2) * 512 + t)) * 8];
            w3.u = *(const uint4*)&wl[((size_t)((lc * 4 + 3) * 512 + t)) * 8];
            sA0 = __builtin_amdgcn_fdot2(w0.h[0], h.h[0], sA0, false);
            sB0 = __builtin_amdgcn_fdot2(w0.h[1], h.h[1], sB0, false);
            sA0 = __builtin_amdgcn_fdot2(w0.h[2], h.h[2], sA0, false);
            sB0 = __builtin_amdgcn_fdot2(w0.h[3], h.h[3], sB0, false);
            sA1 = __builtin_amdgcn_fdot2(w1.h[0], h.h[0], sA1, false);
            sB1 = __builtin_amdgcn_fdot2(w1.h[1], h.h[1], sB1, false);
            sA1 = __builtin_amdgcn_fdot2(w1.h[2], h.h[2], sA1, false);
            sB1 = __builtin_amdgcn_fdot2(w1.h[3], h.h[3], sB1, false);
            sA2 = __builtin_amdgcn_fdot2(w2.h[0], h.h[0], sA2, false);
            sB2 = __builtin_amdgcn_fdot2(w2.h[1], h.h[1], sB2, false);
            sA2 = __builtin_amdgcn_fdot2(w2.h[2], h.h[2], sA2, false);
            sB2 = __builtin_amdgcn_fdot2(w2.h[3], h.h[3], sB2, false);
            sA3 = __builtin_amdgcn_fdot2(w3.h[0], h.h[0], sA3, false);
            sB3 = __builtin_amdgcn_fdot2(w3.h[1], h.h[1], sB3, false);
            sA3 = __builtin_amdgcn_fdot2(w3.h[2], h.h[2], sA3, false);
            sB3 = __builtin_amdgcn_fdot2(w3.h[3], h.h[3], sB3, false);
        }
        // register-weight chunks i = 0..11 (global chunk cb + 4 + i)
        #pragma unroll
        for (int i = 0; i < 12; ++i) {
            U16 h; h.u = *(const uint4*)&hb[(4 + i) * 8];   // disjoint-bank bcast
            U16 w0, w1, w2, w3;
            w0.u = wrg[i][0]; w1.u = wrg[i][1]; w2.u = wrg[i][2]; w3.u = wrg[i][3];
            sA0 = __builtin_amdgcn_fdot2(w0.h[0], h.h[0], sA0, false);
            sB0 = __builtin_amdgcn_fdot2(w0.h[1], h.h[1], sB0, false);
            sA0 = __builtin_amdgcn_fdot2(w0.h[2], h.h[2], sA0, false);
            sB0 = __builtin_amdgcn_fdot2(w0.h[3], h.h[3], sB0, false);
            sA1 = __builtin_amdgcn_fdot2(w1.h[0], h.h[0], sA1, false);
            sB1 = __builtin_amdgcn_fdot2(w1.h[1], h.h[1], sB1, false);
            sA1 = __builtin_amdgcn_fdot2(w1.h[2], h.h[2], sA1, false);
            sB1 = __builtin_amdgcn_fdot2(w1.h[3], h.h[3], sB1, false);
            sA2 = __builtin_amdgcn_fdot2(w2.h[0], h.h[0], sA2, false);
            sB2 = __builtin_amdgcn_fdot2(w2.h[1], h.h[1], sB2, false);
            sA2 = __builtin_amdgcn_fdot2(w2.h[2], h.h[2], sA2, false);
            sB2 = __builtin_amdgcn_fdot2(w2.h[3], h.h[3], sB2, false);
            sA3 = __builtin_amdgcn_fdot2(w3.h[0], h.h[0], sA3, false);
            sB3 = __builtin_amdgcn_fdot2(w3.h[1], h.h[1], sB3, false);
            sA3 = __builtin_amdgcn_fdot2(w3.h[2], h.h[2], sA3, false);
            sB3 = __builtin_amdgcn_fdot2(w3.h[3], h.h[3], sB3, false);
        }
        // combine k-halves across the lane pair (DPP, VALU pipe)
        float P0 = sA0 + sB0, P1 = sA1 + sB1, P2 = sA2 + sB2, P3 = sA3 + sB3;
        float S0 = P0 + QP_XOR1(P0);     // full dot, col 4R+0 (f)
        float S1 = P1 + QP_XOR1(P1);     // col 4R+1 (i)
        float S2 = P2 + QP_XOR1(P2);     // col 4R+2 (g~)
        float S3 = P3 + QP_XOR1(P3);     // col 4R+3 (o)
        float a0 = xa2.x + (podd ? S2 : S0);   // col 2t   (even: f | odd: g~)
        float a1 = xa2.y + (podd ? S3 : S1);   // col 2t+1 (even: i | odd: o)
        float vA = fmaf(aa, sigm_f(sm * a0), bbc);
        float vB = sigm_f(a1);
        float eA = QP_XOR1(vA);            // partner's A value
        float eB = QP_XOR1(vB);            // partner's B value
        float f  = podd ? eA : vA;
        float ii = podd ? eB : vB;
        float gg = podd ? vA : eA;
        float o  = podd ? vB : eB;
        float c  = fmaf(f, creg, ii * gg);
        creg = c;
        float h  = o * tanh_f(c);
        if (!podd) hl[cur ^ 1][hpad(t >> 1)] = (_Float16)h;
        __syncthreads();
        // coalesced out-store post-barrier (drains at next step's barrier)
        if (t < HID)
            out[((size_t)(t0 + tt) * BATCH + b) * HID + t] = (float)hl[cur ^ 1][hpad(t)];
        xa2 = xn2;
        cur ^= 1;
    }
    if (t < HID) hstate[b * HID + t] = (float)hl[cur][hpad(t)];
    if (!podd)   cstate[b * HID + (t >> 1)] = creg;
}

// ---------------- tail: final hx, cx ------------------------------------------
__global__ void tail_kernel(const float* __restrict__ hstate,
                            const float* __restrict__ cstate, float* __restrict__ out) {
    int b = blockIdx.x, r = threadIdx.x;
    size_t base = (size_t)T_SEQ * BATCH * HID;
    out[base + b * HID + r] = hstate[b * HID + r];
    out[base + (size_t)BATCH * HID + b * HID + r] = cstate[b * HID + r];
}

extern "C" void kernel_launch(void* const* d_in, const int* in_sizes, int n_in,
                              void* d_out, int out_size, void* d_ws, size_t ws_size,
                              hipStream_t stream) {
    (void)in_sizes; (void)n_in; (void)out_size;
    const float* X  = (const float*)d_in[0];
    const float* Wf = (const float*)d_in[1];
    const float* bf = (const float*)d_in[2];
    const float* Wi = (const float*)d_in[3];
    const float* bi = (const float*)d_in[4];
    const float* Wg = (const float*)d_in[5];
    const float* bg = (const float*)d_in[6];
    const float* Wo = (const float*)d_in[7];
    const float* bo = (const float*)d_in[8];
    float* out = (float*)d_out;
    char*  ws  = (char*)d_ws;

    const size_t MB = 1 << 20, KB = 1 << 10;
    float*    wx4    = (float*)(ws);                          // 1 MB
    _Float16* whB    = (_Float16*)(ws + MB);                  // 512 KB
    float*    bias4  = (float*)(ws + MB + 512 * KB);          // 4 KB
    float*    hstate = (float*)(ws + MB + 576 * KB);          // 64 KB
    float*    cstate = (float*)(ws + MB + 640 * KB);          // 64 KB
    float4*   xproj  = (float4*)(ws + 2 * MB);

    size_t fixed = 2 * MB;
    int Tc = 1024;
    while (Tc > 16 && fixed + (size_t)Tc * BATCH * NG * 4 > ws_size) Tc >>= 1;

    pack_kernel<<<256, 1024, 0, stream>>>(Wf, bf, Wi, bi, Wg, bg, Wo, bo,
                                          wx4, whB, bias4, hstate, cstate);
    for (int t0 = 0; t0 < T_SEQ; t0 += Tc) {
        xproj_kernel<<<Tc * BATCH / 16, 256, 0, stream>>>(
            X + (size_t)t0 * BATCH * DIM, wx4, bias4, xproj);
        lstm_step_kernel<<<BATCH, 512, 0, stream>>>(
            (const float*)xproj, whB, hstate, cstate, out, t0, Tc);
    }
    tail_kernel<<<BATCH, HID, 0, stream>>>(hstate, cstate, out);
}

// Round 11
// 1751.470 us; speedup vs baseline: 1.9359x; 1.1484x over previous
//
#include <hip/hip_runtime.h>
#include <cstdint>
#include <cstddef>

#define T_SEQ 1024
#define BATCH 64
#define DIM   256
#define HID   256
#define NG    (4*HID)   // 1024 gate columns, jp = 4r + g, g in {f,i,g~,o}
#define HPADN (HID + 8) // h buffer with 16B pad between row-halves (bank shift)

typedef _Float16 h2v __attribute__((ext_vector_type(2)));
union U16 { uint4 u; h2v h[4]; };

__device__ __forceinline__ float sigm_f(float x) {
    return 1.0f / (1.0f + __expf(-x));
}
__device__ __forceinline__ float tanh_f(float x) {
    x = fminf(fmaxf(x, -15.0f), 15.0f);   // avoid inf/inf
    float e = __expf(2.0f * x);
    return (e - 1.0f) / (e + 1.0f);
}

// DPP quad_perm [1,0,3,2] = swap adjacent lane pairs (xor-1), VALU pipe
#define QP_XOR1(x) __int_as_float(__builtin_amdgcn_mov_dpp(__float_as_int(x), 0xB1, 0xf, 0xf, true))

// padded h index: rows 128..255 shifted by 8 halfs (16B) -> odd-lane broadcast
// hits disjoint banks from even-lane broadcast (round-10: conflicts 1.7e7 -> 0)
__device__ __forceinline__ int hpad(int r) { return r + ((r >> 7) << 3); }

// ---------------- phase 0: repack weights, zero state -------------------------
// wx4[k*1024 + jp] = W_g[r][k]            (x part, fp32; jp = 4r+g)
// whB (h part, fp16, k-packs of 8), PAIR-K-SPLIT layout:
//   chunk c = k>>3 (0..31), e = k&7; col jp: R = jp>>2, s = jp&3.
//   k-half p = (c>=16); reader thread t = 2R + p; lc = c - 16p (0..15).
//   lc 0..3  -> LDS region:  uint4 idx =        (lc*4 + s)*512 + t
//   lc 4..15 -> reg region:  uint4 idx = 8192 + ((lc-4)*4 + s)*512 + t
// bias4[jp] = b_g[r]
__global__ void pack_kernel(const float* __restrict__ Wf, const float* __restrict__ bf,
                            const float* __restrict__ Wi, const float* __restrict__ bi,
                            const float* __restrict__ Wg, const float* __restrict__ bg,
                            const float* __restrict__ Wo, const float* __restrict__ bo,
                            float* __restrict__ wx4, _Float16* __restrict__ whB,
                            float* __restrict__ bias4,
                            float* __restrict__ hstate, float* __restrict__ cstate) {
    int k = blockIdx.x;          // 0..255
    int j = threadIdx.x;         // 0..1023
    int r = j & 255, g = j >> 8;
    const float* W  = (g == 0) ? Wf : (g == 1) ? Wi : (g == 2) ? Wg : Wo;
    const float* bb = (g == 0) ? bf : (g == 1) ? bi : (g == 2) ? bg : bo;
    int jp = r * 4 + g;
    wx4[(size_t)k * 1024 + jp] = W[(size_t)r * 512 + k];
    {
        int c = k >> 3, e = k & 7;
        int R = jp >> 2, s = jp & 3;
        int p = (c >= 16) ? 1 : 0;
        int lc = c - 16 * p;                 // 0..15
        int t = 2 * R + p;
        size_t idx = (lc < 4)
            ? ((size_t)(lc * 4 + s) * 512 + t)
            : (8192 + (size_t)((lc - 4) * 4 + s) * 512 + t);
        whB[idx * 8 + e] = (_Float16)W[(size_t)r * 512 + 256 + k];
    }
    if (k == 0) bias4[jp] = bb[r];
    if (k < 64 && g == 0) hstate[k * 256 + r] = 0.0f;
    if (k < 64 && g == 1) cstate[k * 256 + r] = 0.0f;
}

// ---------------- phase 1 (standalone, chunk 0 only) --------------------------
__global__ __launch_bounds__(256) void xproj_kernel(
        const float* __restrict__ X, const float* __restrict__ wx4,
        const float* __restrict__ bias4, float4* __restrict__ xp) {
    __shared__ __align__(16) float xl[256 * 20];   // [k][row] padded
    int tid = threadIdx.x;
    int R0 = blockIdx.x * 16;
    #pragma unroll
    for (int i = 0; i < 16; ++i)
        xl[tid * 20 + i] = X[(size_t)(R0 + i) * DIM + tid];
    __syncthreads();

    float4 bv = ((const float4*)bias4)[tid];
    float acc[16][4];
    #pragma unroll
    for (int i = 0; i < 16; ++i) {
        acc[i][0] = bv.x; acc[i][1] = bv.y; acc[i][2] = bv.z; acc[i][3] = bv.w;
    }
    const float4* __restrict__ wp = (const float4*)wx4 + tid;
    #pragma unroll 2
    for (int k = 0; k < 256; ++k) {
        float4 w  = wp[k << 8];
        float4 xa = *(const float4*)&xl[k * 20 + 0];
        float4 xb = *(const float4*)&xl[k * 20 + 4];
        float4 xc = *(const float4*)&xl[k * 20 + 8];
        float4 xd = *(const float4*)&xl[k * 20 + 12];
        float xr[16] = {xa.x, xa.y, xa.z, xa.w, xb.x, xb.y, xb.z, xb.w,
                        xc.x, xc.y, xc.z, xc.w, xd.x, xd.y, xd.z, xd.w};
        #pragma unroll
        for (int i = 0; i < 16; ++i) {
            acc[i][0] = fmaf(xr[i], w.x, acc[i][0]);
            acc[i][1] = fmaf(xr[i], w.y, acc[i][1]);
            acc[i][2] = fmaf(xr[i], w.z, acc[i][2]);
            acc[i][3] = fmaf(xr[i], w.w, acc[i][3]);
        }
    }
    #pragma unroll
    for (int i = 0; i < 16; ++i) {
        float4 v;
        v.x = acc[i][0]; v.y = acc[i][1]; v.z = acc[i][2]; v.w = acc[i][3];
        xp[(size_t)(R0 + i) * 256 + tid] = v;
    }
}

// ---------------- phase 2: FUSED recurrence + next-chunk xproj riders --------
// blockIdx < 64:  round-10 recurrence (unchanged, 129 KB LDS).
// blockIdx >= 64: xproj rider for the NEXT chunk into xp_write (40 KB LDS,
//   32 rows/WG: threads 0..255 rows R0..R0+15, threads 256..511 next 16).
// Rec and rider CANNOT co-locate on a CU: 129 KB + 40 KB > 160 KB -> riders
// fill only the 192 CUs the recurrence leaves idle. No cross-WG sync; the
// ping-pong xp regions are disjoint; stream order publishes rider output
// before the next dispatch's recurrence reads it.
struct RecSh { _Float16 wl[16 * 512 * 8]; _Float16 hl[2][HPADN]; };
struct XpSh  { float xl[2][256 * 20]; };
union FusedSh { RecSh rec; XpSh xpj; };

__global__ __launch_bounds__(512, 2) void lstm_fused_kernel(
        const float* __restrict__ xp_read, float4* __restrict__ xp_write,
        const float* __restrict__ Xnext, const float* __restrict__ wx4,
        const float* __restrict__ bias4, const _Float16* __restrict__ whB,
        float* __restrict__ hstate, float* __restrict__ cstate,
        float* __restrict__ out, int t0, int Tc) {
    __shared__ __align__(16) FusedSh sh;
    int t = threadIdx.x;

    if (blockIdx.x >= BATCH) {
        // ---------------- xproj rider: 32 rows of the next chunk ----------
        int vb = blockIdx.x - BATCH;
        int half = t >> 8;           // 0 or 1 (wave-uniform)
        int tid = t & 255;
        int R0 = vb * 32 + half * 16;
        float* xl = sh.xpj.xl[half];
        #pragma unroll
        for (int i = 0; i < 16; ++i)
            xl[tid * 20 + i] = Xnext[(size_t)(R0 + i) * DIM + tid];
        __syncthreads();

        float4 bv = ((const float4*)bias4)[tid];
        float acc[16][4];
        #pragma unroll
        for (int i = 0; i < 16; ++i) {
            acc[i][0] = bv.x; acc[i][1] = bv.y; acc[i][2] = bv.z; acc[i][3] = bv.w;
        }
        const float4* __restrict__ wp = (const float4*)wx4 + tid;
        #pragma unroll 2
        for (int k = 0; k < 256; ++k) {
            float4 w  = wp[k << 8];
            float4 xa = *(const float4*)&xl[k * 20 + 0];
            float4 xb = *(const float4*)&xl[k * 20 + 4];
            float4 xc = *(const float4*)&xl[k * 20 + 8];
            float4 xd = *(const float4*)&xl[k * 20 + 12];
            float xr[16] = {xa.x, xa.y, xa.z, xa.w, xb.x, xb.y, xb.z, xb.w,
                            xc.x, xc.y, xc.z, xc.w, xd.x, xd.y, xd.z, xd.w};
            #pragma unroll
            for (int i = 0; i < 16; ++i) {
                acc[i][0] = fmaf(xr[i], w.x, acc[i][0]);
                acc[i][1] = fmaf(xr[i], w.y, acc[i][1]);
                acc[i][2] = fmaf(xr[i], w.z, acc[i][2]);
                acc[i][3] = fmaf(xr[i], w.w, acc[i][3]);
            }
        }
        #pragma unroll
        for (int i = 0; i < 16; ++i) {
            float4 v;
            v.x = acc[i][0]; v.y = acc[i][1]; v.z = acc[i][2]; v.w = acc[i][3];
            xp_write[(size_t)(R0 + i) * 256 + tid] = v;
        }
        return;
    }

    // ---------------- recurrence (round-10 winner, verbatim) --------------
    _Float16* wl = sh.rec.wl;
    int b = blockIdx.x;

    // stage LDS region (8192 uint4 over 512 threads = 16 each)
    {
        const uint4* src = (const uint4*)whB;
        uint4* dst = (uint4*)wl;
        #pragma unroll
        for (int i = 0; i < 16; ++i)
            dst[i * 512 + t] = src[i * 512 + t];
    }
    // register slab: 12 chunks x 4 cols for this thread's k-half (48 uint4)
    uint4 wrg[12][4];
    {
        const uint4* src = (const uint4*)whB + 8192;
        #pragma unroll
        for (int i = 0; i < 12; ++i)
            #pragma unroll
            for (int s = 0; s < 4; ++s)
                wrg[i][s] = src[(size_t)((i * 4 + s) * 512) + t];
    }
    int podd = t & 1;
    float creg = cstate[b * HID + (t >> 1)];       // pair-replicated (row R)
    if (t < HID) sh.rec.hl[0][hpad(t)] = (_Float16)hstate[b * HID + t];
    // branchless gate-A activation: even: sigm(x); odd: tanh(x)=2*sigm(2x)-1
    float sm = podd ? 2.0f : 1.0f;
    float aa = sm, bbc = podd ? -1.0f : 0.0f;
    int hbase = (podd << 7) + (podd << 3);         // cb*8 + pad = podd*(128+8)
    __syncthreads();

    const float2* __restrict__ xpf2 = (const float2*)xp_read;
    float2 xa2 = xpf2[(size_t)b * 512 + t];
    int cur = 0;
    for (int tt = 0; tt < Tc; ++tt) {
        // prefetch next step's xp early (hides latency under the dot chain)
        int tn = (tt + 1 < Tc) ? tt + 1 : tt;
        float2 xn2 = xpf2[((size_t)tn * BATCH + b) * 512 + t];

        float sA0 = 0.f, sB0 = 0.f, sA1 = 0.f, sB1 = 0.f;
        float sA2 = 0.f, sB2 = 0.f, sA3 = 0.f, sB3 = 0.f;
        const _Float16* hb = &sh.rec.hl[cur][hbase];
        // LDS-weight chunks lc = 0..3 of this thread's k-half
        #pragma unroll
        for (int lc = 0; lc < 4; ++lc) {
            U16 h; h.u = *(const uint4*)&hb[lc * 8];        // disjoint-bank bcast
            U16 w0, w1, w2, w3;
            w0.u = *(const uint4*)&wl[((size_t)((lc * 4 + 0) * 512 + t)) * 8];
            w1.u = *(const uint4*)&wl[((size_t)((lc * 4 + 1) * 512 + t)) * 8];
            w2.u = *(const uint4*)&wl[((size_t)((lc * 4 + 2) * 512 + t)) * 8];
            w3.u = *(const uint4*)&wl[((size_t)((lc * 4 + 3) * 512 + t)) * 8];
            sA0 = __builtin_amdgcn_fdot2(w0.h[0], h.h[0], sA0, false);
            sB0 = __builtin_amdgcn_fdot2(w0.h[1], h.h[1], sB0, false);
            sA0 = __builtin_amdgcn_fdot2(w0.h[2], h.h[2], sA0, false);
            sB0 = __builtin_amdgcn_fdot2(w0.h[3], h.h[3], sB0, false);
            sA1 = __builtin_amdgcn_fdot2(w1.h[0], h.h[0], sA1, false);
            sB1 = __builtin_amdgcn_fdot2(w1.h[1], h.h[1], sB1, false);
            sA1 = __builtin_amdgcn_fdot2(w1.h[2], h.h[2], sA1, false);
            sB1 = __builtin_amdgcn_fdot2(w1.h[3], h.h[3], sB1, false);
            sA2 = __builtin_amdgcn_fdot2(w2.h[0], h.h[0], sA2, false);
            sB2 = __builtin_amdgcn_fdot2(w2.h[1], h.h[1], sB2, false);
            sA2 = __builtin_amdgcn_fdot2(w2.h[2], h.h[2], sA2, false);
            sB2 = __builtin_amdgcn_fdot2(w2.h[3], h.h[3], sB2, false);
            sA3 = __builtin_amdgcn_fdot2(w3.h[0], h.h[0], sA3, false);
            sB3 = __builtin_amdgcn_fdot2(w3.h[1], h.h[1], sB3, false);
            sA3 = __builtin_amdgcn_fdot2(w3.h[2], h.h[2], sA3, false);
            sB3 = __builtin_amdgcn_fdot2(w3.h[3], h.h[3], sB3, false);
        }
        // register-weight chunks i = 0..11 (global chunk cb + 4 + i)
        #pragma unroll
        for (int i = 0; i < 12; ++i) {
            U16 h; h.u = *(const uint4*)&hb[(4 + i) * 8];   // disjoint-bank bcast
            U16 w0, w1, w2, w3;
            w0.u = wrg[i][0]; w1.u = wrg[i][1]; w2.u = wrg[i][2]; w3.u = wrg[i][3];
            sA0 = __builtin_amdgcn_fdot2(w0.h[0], h.h[0], sA0, false);
            sB0 = __builtin_amdgcn_fdot2(w0.h[1], h.h[1], sB0, false);
            sA0 = __builtin_amdgcn_fdot2(w0.h[2], h.h[2], sA0, false);
            sB0 = __builtin_amdgcn_fdot2(w0.h[3], h.h[3], sB0, false);
            sA1 = __builtin_amdgcn_fdot2(w1.h[0], h.h[0], sA1, false);
            sB1 = __builtin_amdgcn_fdot2(w1.h[1], h.h[1], sB1, false);
            sA1 = __builtin_amdgcn_fdot2(w1.h[2], h.h[2], sA1, false);
            sB1 = __builtin_amdgcn_fdot2(w1.h[3], h.h[3], sB1, false);
            sA2 = __builtin_amdgcn_fdot2(w2.h[0], h.h[0], sA2, false);
            sB2 = __builtin_amdgcn_fdot2(w2.h[1], h.h[1], sB2, false);
            sA2 = __builtin_amdgcn_fdot2(w2.h[2], h.h[2], sA2, false);
            sB2 = __builtin_amdgcn_fdot2(w2.h[3], h.h[3], sB2, false);
            sA3 = __builtin_amdgcn_fdot2(w3.h[0], h.h[0], sA3, false);
            sB3 = __builtin_amdgcn_fdot2(w3.h[1], h.h[1], sB3, false);
            sA3 = __builtin_amdgcn_fdot2(w3.h[2], h.h[2], sA3, false);
            sB3 = __builtin_amdgcn_fdot2(w3.h[3], h.h[3], sB3, false);
        }
        // combine k-halves across the lane pair (DPP, VALU pipe)
        float P0 = sA0 + sB0, P1 = sA1 + sB1, P2 = sA2 + sB2, P3 = sA3 + sB3;
        float S0 = P0 + QP_XOR1(P0);     // full dot, col 4R+0 (f)
        float S1 = P1 + QP_XOR1(P1);     // col 4R+1 (i)
        float S2 = P2 + QP_XOR1(P2);     // col 4R+2 (g~)
        float S3 = P3 + QP_XOR1(P3);     // col 4R+3 (o)
        float a0 = xa2.x + (podd ? S2 : S0);   // col 2t   (even: f | odd: g~)
        float a1 = xa2.y + (podd ? S3 : S1);   // col 2t+1 (even: i | odd: o)
        float vA = fmaf(aa, sigm_f(sm * a0), bbc);
        float vB = sigm_f(a1);
        float eA = QP_XOR1(vA);            // partner's A value
        float eB = QP_XOR1(vB);            // partner's B value
        float f  = podd ? eA : vA;
        float ii = podd ? eB : vB;
        float gg = podd ? vA : eA;
        float o  = podd ? vB : eB;
        float c  = fmaf(f, creg, ii * gg);
        creg = c;
        float h  = o * tanh_f(c);
        if (!podd) sh.rec.hl[cur ^ 1][hpad(t >> 1)] = (_Float16)h;
        __syncthreads();
        // coalesced out-store post-barrier (drains at next step's barrier)
        if (t < HID)
            out[((size_t)(t0 + tt) * BATCH + b) * HID + t] = (float)sh.rec.hl[cur ^ 1][hpad(t)];
        xa2 = xn2;
        cur ^= 1;
    }
    if (t < HID) hstate[b * HID + t] = (float)sh.rec.hl[cur][hpad(t)];
    if (!podd)   cstate[b * HID + (t >> 1)] = creg;
}

// ---------------- tail: final hx, cx ------------------------------------------
__global__ void tail_kernel(const float* __restrict__ hstate,
                            const float* __restrict__ cstate, float* __restrict__ out) {
    int b = blockIdx.x, r = threadIdx.x;
    size_t base = (size_t)T_SEQ * BATCH * HID;
    out[base + b * HID + r] = hstate[b * HID + r];
    out[base + (size_t)BATCH * HID + b * HID + r] = cstate[b * HID + r];
}

extern "C" void kernel_launch(void* const* d_in, const int* in_sizes, int n_in,
                              void* d_out, int out_size, void* d_ws, size_t ws_size,
                              hipStream_t stream) {
    (void)in_sizes; (void)n_in; (void)out_size;
    const float* X  = (const float*)d_in[0];
    const float* Wf = (const float*)d_in[1];
    const float* bf = (const float*)d_in[2];
    const float* Wi = (const float*)d_in[3];
    const float* bi = (const float*)d_in[4];
    const float* Wg = (const float*)d_in[5];
    const float* bg = (const float*)d_in[6];
    const float* Wo = (const float*)d_in[7];
    const float* bo = (const float*)d_in[8];
    float* out = (float*)d_out;
    char*  ws  = (char*)d_ws;

    const size_t MB = 1 << 20, KB = 1 << 10;
    float*    wx4    = (float*)(ws);                          // 1 MB
    _Float16* whB    = (_Float16*)(ws + MB);                  // 512 KB
    float*    bias4  = (float*)(ws + MB + 512 * KB);          // 4 KB
    float*    hstate = (float*)(ws + MB + 576 * KB);          // 64 KB
    float*    cstate = (float*)(ws + MB + 640 * KB);          // 64 KB

    // ping-pong xproj regions (double-buffered so riders for chunk i+1 write
    // while the recurrence reads chunk i)
    int Tc = 256;
    while (Tc > 16 && 2 * MB + 2 * (size_t)Tc * BATCH * NG * 4 > ws_size) Tc >>= 1;
    int Nc = T_SEQ / Tc;
    size_t xpBytes = (size_t)Tc * BATCH * NG * 4;
    float4* xpA = (float4*)(ws + 2 * MB);
    float4* xpB = (float4*)(ws + 2 * MB + xpBytes);

    pack_kernel<<<256, 1024, 0, stream>>>(Wf, bf, Wi, bi, Wg, bg, Wo, bo,
                                          wx4, whB, bias4, hstate, cstate);
    // chunk 0 projection (exposed once)
    xproj_kernel<<<Tc * BATCH / 16, 256, 0, stream>>>(X, wx4, bias4, xpA);
    for (int i = 0; i < Nc; ++i) {
        float4* rd = (i & 1) ? xpB : xpA;
        float4* wr = (i & 1) ? xpA : xpB;
        int nxp = (i < Nc - 1) ? (Tc * BATCH / 32) : 0;
        lstm_fused_kernel<<<BATCH + nxp, 512, 0, stream>>>(
            (const float*)rd, wr, X + (size_t)(i + 1) * Tc * BATCH * DIM,
            wx4, bias4, whB, hstate, cstate, out, i * Tc, Tc);
    }
    tail_kernel<<<BATCH, HID, 0, stream>>>(hstate, cstate, out);
}